// Round 10
// baseline (51.276 us; speedup 1.0000x reference)
//
#include <hip/hip_runtime.h>

// SoftErosion3D, connectivity=6, iterations=2, [2,1,256,256,256] f32.
//   iter1(x) = x^2 * prod(6 face nbrs), pad 1.0 ; out = iter1(iter1(im))
// Fused, no LDS, no barriers. Wave = full W row (64 lanes x float4); w+-1 via
// intra-wave shuffles. Thread owns rows h,h+1. R9: A/B — REGULAR stores
// instead of nontemporal (test whether NT write path was the 47us limiter).

#define DD 256
#define HH 256
#define HW 65536
#define DT 16

typedef float nfloat4 __attribute__((ext_vector_type(4)));

__device__ __forceinline__ float wleft(float x) {     // lane-1's x ; lane0 -> 1.0
    float v = __shfl_up(x, 1, 64);
    return ((threadIdx.x & 63) == 0) ? 1.0f : v;
}
__device__ __forceinline__ float wright(float x) {    // lane+1's x ; lane63 -> 1.0
    float v = __shfl_down(x, 1, 64);
    return ((threadIdx.x & 63) == 63) ? 1.0f : v;
}
__device__ __forceinline__ float4 f4mul(float4 a, float4 b) {
    a.x *= b.x; a.y *= b.y; a.z *= b.z; a.w *= b.w; return a;
}
__device__ __forceinline__ float4 i1core(float4 c) {  // c^2 * W-neighbors
    float lw = wleft(c.w), rw = wright(c.x);
    float4 r;
    r.x = c.x * c.x * (lw  * c.y);
    r.y = c.y * c.y * (c.x * c.z);
    r.z = c.z * c.z * (c.y * c.w);
    r.w = c.w * c.w * (c.z * rw);
    return r;
}
__device__ __forceinline__ int dcl(int d) { return d < 0 ? 0 : (d > DD - 1 ? DD - 1 : d); }

__global__ __launch_bounds__(256) void erode6_fused(const float* __restrict__ in,
                                                    float* __restrict__ out) {
    const int bx  = blockIdx.x;
    const int swz = (bx & 7) * 128 + (bx >> 3);   // 1024 blocks, bijective XCD chunking

    const int cc = threadIdx.x & 63;              // f4 column, w = cc*4
    const int wv = __builtin_amdgcn_readfirstlane((int)(threadIdx.x >> 6));

    const int hblk = swz & 31;          // 32 H-blocks of 8 rows
    const int dchk = (swz >> 5) & 15;   // 16 D-chunks of 16 planes
    const int b    = swz >> 9;          // batch

    const int h = hblk * 8 + wv * 2;    // own rows h, h+1
    const int S = dchk * DT;

    const bool vbU = (h >= 1);
    const bool voU = (h >= 2);
    const bool vbD = (h + 2 <= HH - 1);
    const bool voD = (h + 3 <= HH - 1);
    const int rowU  = vbU ? h - 1 : 0;
    const int rowOU = voU ? h - 2 : 0;
    const int rowD  = vbD ? h + 2 : HH - 1;
    const int rowOD = voD ? h + 3 : HH - 1;

    const float* __restrict__ ip = in  + (size_t)b * (DD * HW);
    float* __restrict__       op = out + (size_t)b * (DD * HW);

    const float* pC0 = ip + (h     << 8) + (cc << 2);
    const float* pC1 = ip + ((h+1) << 8) + (cc << 2);
    const float* pBU = ip + (rowU  << 8) + (cc << 2);
    const float* pBD = ip + (rowD  << 8) + (cc << 2);
    const float* pOU = ip + (rowOU << 8) + (cc << 2);
    const float* pOD = ip + (rowOD << 8) + (cc << 2);
    float* pO0 = op + (h << 8) + (cc << 2);

#define LD(p, pl) (*reinterpret_cast<const float4*>((p) + ((pl) << 16)))

    const int Sm1 = S >= 1 ? S - 1 : 0;
    const int Sm2 = S >= 2 ? S - 2 : 0;

    // ---- prologue loads ----
    float4 c0_m2 = LD(pC0, Sm2), c0_m1 = LD(pC0, Sm1);
    float4 c0_t  = LD(pC0, S), c0_t1 = LD(pC0, S + 1), c0_t2 = LD(pC0, S + 2);
    float4 c1_m2 = LD(pC1, Sm2), c1_m1 = LD(pC1, Sm1);
    float4 c1_t  = LD(pC1, S), c1_t1 = LD(pC1, S + 1), c1_t2 = LD(pC1, S + 2);
    float4 bu_m = LD(pBU, Sm1), bu_c = LD(pBU, S), bu_p = LD(pBU, S + 1);
    float4 bd_m = LD(pBD, Sm1), bd_c = LD(pBD, S), bd_p = LD(pBD, S + 1);
    float4 ou = LD(pOU, S), od = LD(pOD, S);

    // i*_m = iter1(S-1, row) — garbage at S==0, never used (guarded by fm)
    float4 i0_m = i1core(c0_m1);
    i0_m = f4mul(i0_m, c0_t);
    if (S >= 2) i0_m = f4mul(i0_m, c0_m2);
    if (vbU)    i0_m = f4mul(i0_m, bu_m);
    i0_m = f4mul(i0_m, c1_m1);

    float4 i1_m = i1core(c1_m1);
    i1_m = f4mul(i1_m, c1_t);
    if (S >= 2) i1_m = f4mul(i1_m, c1_m2);
    i1_m = f4mul(i1_m, c0_m1);
    if (vbD)    i1_m = f4mul(i1_m, bd_m);

    // i*_c = iter1(S, row)
    float4 i0_c = i1core(c0_t);
    if (S >= 1) i0_c = f4mul(i0_c, c0_m1);
    i0_c = f4mul(i0_c, c0_t1);
    if (vbU)    i0_c = f4mul(i0_c, bu_c);
    i0_c = f4mul(i0_c, c1_t);

    float4 i1_c = i1core(c1_t);
    if (S >= 1) i1_c = f4mul(i1_c, c1_m1);
    i1_c = f4mul(i1_c, c1_t1);
    i1_c = f4mul(i1_c, c0_t);
    if (vbD)    i1_c = f4mul(i1_c, bd_c);

#pragma unroll
    for (int k = 0; k < DT; ++k) {
        const int t = S + k;

        // ---- 1-deep prefetch for next step ----
        float4 pf_c0 = LD(pC0, dcl(t + 3)), pf_c1 = LD(pC1, dcl(t + 3));
        float4 pf_bu = LD(pBU, dcl(t + 2)), pf_bd = LD(pBD, dcl(t + 2));
        float4 pf_ou = LD(pOU, dcl(t + 1)), pf_od = LD(pOD, dcl(t + 1));

        const bool fm  = (t > 0);
        const bool fp  = (t < DD - 1);
        const bool fD2 = (t < DD - 2);

        // ---- boundary-row iter1 at plane t ----
        float4 IbU = {1.f, 1.f, 1.f, 1.f};
        if (vbU) {
            IbU = i1core(bu_c);
            if (fm)  IbU = f4mul(IbU, bu_m);
            if (fp)  IbU = f4mul(IbU, bu_p);
            if (voU) IbU = f4mul(IbU, ou);
            IbU = f4mul(IbU, c0_t);
        }
        float4 IbD = {1.f, 1.f, 1.f, 1.f};
        if (vbD) {
            IbD = i1core(bd_c);
            if (fm)  IbD = f4mul(IbD, bd_m);
            if (fp)  IbD = f4mul(IbD, bd_p);
            IbD = f4mul(IbD, c1_t);
            if (voD) IbD = f4mul(IbD, od);
        }

        // ---- iter1(t+1, own rows) ----
        float4 i0_p = i1core(c0_t1);
        i0_p = f4mul(i0_p, c0_t);
        if (fD2) i0_p = f4mul(i0_p, c0_t2);
        if (vbU) i0_p = f4mul(i0_p, bu_p);
        i0_p = f4mul(i0_p, c1_t1);

        float4 i1_p = i1core(c1_t1);
        i1_p = f4mul(i1_p, c1_t);
        if (fD2) i1_p = f4mul(i1_p, c1_t2);
        i1_p = f4mul(i1_p, c0_t1);
        if (vbD) i1_p = f4mul(i1_p, bd_p);

        // ---- iter2 outputs at plane t ----
        float4 o0 = i1core(i0_c);
        if (fm) o0 = f4mul(o0, i0_m);
        if (fp) o0 = f4mul(o0, i0_p);
        o0 = f4mul(o0, IbU);
        o0 = f4mul(o0, i1_c);       // row h+1's iter1 — in-register H-neighbor

        float4 o1 = i1core(i1_c);
        if (fm) o1 = f4mul(o1, i1_m);
        if (fp) o1 = f4mul(o1, i1_p);
        o1 = f4mul(o1, i0_c);
        o1 = f4mul(o1, IbD);

        // R9 A/B: regular cached stores (were nontemporal)
        *reinterpret_cast<float4*>(pO0 + (t << 16)) = o0;
        *reinterpret_cast<float4*>(pO0 + (t << 16) + 256) = o1;

        // ---- roll (register renaming under full unroll) ----
        i0_m = i0_c; i0_c = i0_p; i1_m = i1_c; i1_c = i1_p;
        c0_t = c0_t1; c0_t1 = c0_t2; c0_t2 = pf_c0;
        c1_t = c1_t1; c1_t1 = c1_t2; c1_t2 = pf_c1;
        bu_m = bu_c; bu_c = bu_p; bu_p = pf_bu;
        bd_m = bd_c; bd_c = bd_p; bd_p = pf_bd;
        ou = pf_ou; od = pf_od;
    }
#undef LD
}

extern "C" void kernel_launch(void* const* d_in, const int* in_sizes, int n_in,
                              void* d_out, int out_size, void* d_ws, size_t ws_size,
                              hipStream_t stream) {
    const float* in  = (const float*)d_in[0];
    float*       out = (float*)d_out;

    // 32 H-blocks (8 rows) * 16 D-chunks (16 planes) * 2 batch = 1024 blocks
    dim3 block(256);
    dim3 grid(1024);
    erode6_fused<<<grid, block, 0, stream>>>(in, out);
}